// Round 10
// baseline (4301.604 us; speedup 1.0000x reference)
//
#include <hip/hip_runtime.h>
#include <hip/hip_bf16.h>

#define S_ 64
#define B_ 32
#define V_ 32000
#define E_ 512
#define H_ 1024
#define H3_ 3072

typedef __hip_bfloat16 bf16;
typedef __attribute__((ext_vector_type(8))) short s8v;
typedef __attribute__((ext_vector_type(4))) float f4;
typedef unsigned long long ull;

__device__ __forceinline__ float b2f(bf16 x){ return __bfloat162float(x); }
__device__ __forceinline__ bf16  f2b(float x){ return __float2bfloat16(x); }
__device__ __forceinline__ float bfu2f(unsigned short u){
  union { unsigned u; float f; } c; c.u = ((unsigned)u) << 16; return c.f;
}
#define MFMA16(a,b,c) __builtin_amdgcn_mfma_f32_16x16x32_bf16((a),(b),(c),0,0,0)

__device__ __forceinline__ float fsigmoid(float x){ return 1.f/(1.f + __expf(-x)); }
__device__ __forceinline__ float ftanh(float x){ float e2 = __expf(2.f*x); return 1.f - 2.f/(e2 + 1.f); }

// ---- prep kernels ----
__global__ __launch_bounds__(256) void cast_bf16_k(const float* __restrict__ s, bf16* __restrict__ d, int n8){
  int stride = gridDim.x*256;
  for (int i = blockIdx.x*256 + threadIdx.x; i < n8; i += stride){
    f4 a = *((const f4*)s + (size_t)i*2);
    f4 b = *((const f4*)s + (size_t)i*2 + 1);
    union { s8v v; bf16 h[8]; } o;
    #pragma unroll
    for (int k=0;k<4;k++){ o.h[k]=f2b(a[k]); o.h[4+k]=f2b(b[k]); }
    *((s8v*)d + i) = o.v;
  }
}
__global__ __launch_bounds__(256) void cast2_k(const float* __restrict__ s0, const float* __restrict__ s1,
                                               bf16* __restrict__ d0, bf16* __restrict__ d1, int n8){
  const float* s = blockIdx.y ? s1 : s0;
  bf16* d = blockIdx.y ? d1 : d0;
  int stride = gridDim.x*256;
  for (int i = blockIdx.x*256 + threadIdx.x; i < n8; i += stride){
    f4 a = *((const f4*)s + (size_t)i*2);
    f4 b = *((const f4*)s + (size_t)i*2 + 1);
    union { s8v v; bf16 h[8]; } o;
    #pragma unroll
    for (int k=0;k<4;k++){ o.h[k]=f2b(a[k]); o.h[4+k]=f2b(b[k]); }
    *((s8v*)d + i) = o.v;
  }
}
__global__ __launch_bounds__(256) void cast4_k(const float* __restrict__ s0, const float* __restrict__ s1,
                                               const float* __restrict__ s2, const float* __restrict__ s3,
                                               bf16* __restrict__ d0, bf16* __restrict__ d1,
                                               bf16* __restrict__ d2, bf16* __restrict__ d3, int n8){
  const float* s = (blockIdx.y==0)?s0:(blockIdx.y==1)?s1:(blockIdx.y==2)?s2:s3;
  bf16* d = (blockIdx.y==0)?d0:(blockIdx.y==1)?d1:(blockIdx.y==2)?d2:d3;
  int stride = gridDim.x*256;
  for (int i = blockIdx.x*256 + threadIdx.x; i < n8; i += stride){
    f4 a = *((const f4*)s + (size_t)i*2);
    f4 b = *((const f4*)s + (size_t)i*2 + 1);
    union { s8v v; bf16 h[8]; } o;
    #pragma unroll
    for (int k=0;k<4;k++){ o.h[k]=f2b(a[k]); o.h[4+k]=f2b(b[k]); }
    *((s8v*)d + i) = o.v;
  }
}
// merged gathers: y=0 -> x_b from iseq; y=1 -> lo_b from tseq/dino
__global__ __launch_bounds__(256) void gather2_k(const float* __restrict__ emb,
                                                 const int* __restrict__ iseq, const int* __restrict__ tseq,
                                                 const float* __restrict__ o0,
                                                 bf16* __restrict__ dx, bf16* __restrict__ dlo){
  int i = blockIdx.x*256 + threadIdx.x;
  int row = i >> 6, e8 = i & 63;
  const float* src;
  bf16* d;
  if (blockIdx.y == 0){
    src = emb + (size_t)iseq[row]*E_;
    d = dx;
  } else {
    int t = row >> 5, b = row & 31;
    src = (t == 0) ? o0 : (emb + (size_t)tseq[(t-1)*B_ + b]*E_);
    d = dlo;
  }
  f4 a = *((const f4*)src + e8*2);
  f4 b = *((const f4*)src + e8*2 + 1);
  union { s8v v; bf16 h[8]; } o;
  #pragma unroll
  for (int k=0;k<4;k++){ o.h[k]=f2b(a[k]); o.h[4+k]=f2b(b[k]); }
  *((s8v*)d + i) = o.v;
}

// ---- generic bf16 MFMA GEMM ----
template<int WB16, int ACC>
__global__ __launch_bounds__(256) void gemm_bt(const bf16* __restrict__ A, int lda,
                                               const bf16* __restrict__ B, int ldb,
                                               const float* __restrict__ bias,
                                               void* __restrict__ Cp, int ldc, int K)
{
  __shared__ bf16 a_sm[128][40];
  __shared__ bf16 b_sm[128][40];
  const int tid = threadIdx.x;
  const int m0 = blockIdx.y*128, n0 = blockIdx.x*128;
  const int w = tid>>6, l = tid&63;
  const int wm = w>>1, wn = w&1;
  f4 acc[4][4];
  #pragma unroll
  for (int i=0;i<4;i++)
    #pragma unroll
    for (int j=0;j<4;j++) acc[i][j] = (f4){0.f,0.f,0.f,0.f};
  const int srow = tid>>1, skc = (tid&1)*16;
  const int ar = l&15, koff = (l>>4)*8;
  for (int k0 = 0; k0 < K; k0 += 32){
    __syncthreads();
    const s8v* pa = (const s8v*)(A + (size_t)(m0+srow)*lda + k0 + skc);
    const s8v* pb = (const s8v*)(B + (size_t)(n0+srow)*ldb + k0 + skc);
    *(s8v*)&a_sm[srow][skc]   = pa[0];
    *(s8v*)&a_sm[srow][skc+8] = pa[1];
    *(s8v*)&b_sm[srow][skc]   = pb[0];
    *(s8v*)&b_sm[srow][skc+8] = pb[1];
    __syncthreads();
    s8v av[4], bv[4];
    #pragma unroll
    for (int i=0;i<4;i++) av[i] = *(const s8v*)&a_sm[wm*64 + i*16 + ar][koff];
    #pragma unroll
    for (int j=0;j<4;j++) bv[j] = *(const s8v*)&b_sm[wn*64 + j*16 + ar][koff];
    #pragma unroll
    for (int i=0;i<4;i++)
      #pragma unroll
      for (int j=0;j<4;j++)
        acc[i][j] = MFMA16(av[i], bv[j], acc[i][j]);
  }
  const int rb = (l>>4)*4;
  #pragma unroll
  for (int i=0;i<4;i++){
    #pragma unroll
    for (int j=0;j<4;j++){
      int col = n0 + wn*64 + j*16 + ar;
      float badd = bias ? bias[col] : 0.f;
      #pragma unroll
      for (int r=0;r<4;r++){
        int row = m0 + wm*64 + i*16 + rb + r;
        size_t idx = (size_t)row*ldc + col;
        float v = acc[i][j][r] + badd;
        if (ACC) v += ((const float*)Cp)[idx];
        if (WB16) ((bf16*)Cp)[idx] = f2b(v);
        else      ((float*)Cp)[idx] = v;
      }
    }
  }
}

// ---- output-projection GEMM: XCD-supertile swizzle, bf16 logits out ----
__global__ __launch_bounds__(256) void out_gemm_k(
  const bf16* __restrict__ A, const bf16* __restrict__ Bw,
  const float* __restrict__ bias, bf16* __restrict__ C)
{
  __shared__ bf16 a_sm[128][40];
  __shared__ bf16 b_sm[128][40];
  const int tid = threadIdx.x;
  const int bid = blockIdx.x;
  const int xcd = bid & 7, kk = bid >> 3;
  const int super = kk >> 6, rem = kk & 63;
  const int sm = super & 1, sn = super >> 1;
  const int mi = rem & 7, nj = rem >> 3;
  const int mt = sm*8 + mi, nl = sn*8 + nj;
  const int nt = nl*8 + xcd;
  if (nt >= 250) return;
  const int m0 = mt*128, n0 = nt*128;
  const int w = tid>>6, l = tid&63;
  const int wm = w>>1, wn = w&1;
  f4 acc[4][4];
  #pragma unroll
  for (int i=0;i<4;i++)
    #pragma unroll
    for (int j=0;j<4;j++) acc[i][j] = (f4){0.f,0.f,0.f,0.f};
  const int srow = tid>>1, skc = (tid&1)*16;
  const int ar = l&15, koff = (l>>4)*8;
  for (int k0 = 0; k0 < 1024; k0 += 32){
    __syncthreads();
    const s8v* pa = (const s8v*)(A + (size_t)(m0+srow)*1024 + k0 + skc);
    const s8v* pb = (const s8v*)(Bw + (size_t)(n0+srow)*1024 + k0 + skc);
    *(s8v*)&a_sm[srow][skc]   = pa[0];
    *(s8v*)&a_sm[srow][skc+8] = pa[1];
    *(s8v*)&b_sm[srow][skc]   = pb[0];
    *(s8v*)&b_sm[srow][skc+8] = pb[1];
    __syncthreads();
    s8v av[4], bv[4];
    #pragma unroll
    for (int i=0;i<4;i++) av[i] = *(const s8v*)&a_sm[wm*64 + i*16 + ar][koff];
    #pragma unroll
    for (int j=0;j<4;j++) bv[j] = *(const s8v*)&b_sm[wn*64 + j*16 + ar][koff];
    #pragma unroll
    for (int i=0;i<4;i++)
      #pragma unroll
      for (int j=0;j<4;j++)
        acc[i][j] = MFMA16(av[i], bv[j], acc[i][j]);
  }
  const int rb = (l>>4)*4;
  float bj[4];
  #pragma unroll
  for (int j=0;j<4;j++) bj[j] = bias[n0 + wn*64 + j*16 + ar];
  #pragma unroll
  for (int i=0;i<4;i++){
    #pragma unroll
    for (int j=0;j<4;j++){
      const int col = n0 + wn*64 + j*16 + ar;
      #pragma unroll
      for (int r=0;r<4;r++){
        const int row = m0 + wm*64 + i*16 + rb + r;
        C[(size_t)row*V_ + col] = f2b(acc[i][j][r] + bj[j]);
      }
    }
  }
}

// ---- logit stats: per-row max + sumexp from bf16 logits ----
__global__ __launch_bounds__(256) void logit_stats_k(const bf16* __restrict__ lg,
                                                     float* __restrict__ rowM, float* __restrict__ rowL){
  __shared__ float wm[4], wl[4];
  const int tid = threadIdx.x;
  const bf16* p = lg + (size_t)blockIdx.x*V_;
  float m = -1e30f, lsum = 0.f;
  for (int c = tid; c < V_/8; c += 256){
    union { s8v v; unsigned short us[8]; } u;
    u.v = *((const s8v*)p + c);
    #pragma unroll
    for (int k = 0; k < 8; ++k){
      float v = bfu2f(u.us[k]);
      float mn = fmaxf(m, v);
      lsum = lsum*__expf(m - mn) + __expf(v - mn);
      m = mn;
    }
  }
  #pragma unroll
  for (int o = 32; o; o >>= 1){
    float mo = __shfl_xor(m, o), lo_ = __shfl_xor(lsum, o);
    float mn = fmaxf(m, mo);
    lsum = lsum*__expf(m - mn) + lo_*__expf(mo - mn);
    m = mn;
  }
  if ((tid&63)==0){ wm[tid>>6] = m; wl[tid>>6] = lsum; }
  __syncthreads();
  if (tid == 0){
    float M = fmaxf(fmaxf(wm[0],wm[1]), fmaxf(wm[2],wm[3]));
    float L = wl[0]*__expf(wm[0]-M) + wl[1]*__expf(wm[1]-M)
            + wl[2]*__expf(wm[2]-M) + wl[3]*__expf(wm[3]-M);
    rowM[blockIdx.x] = M;
    rowL[blockIdx.x] = L;
  }
}

// ---- normalize: probs f32 from bf16 logits ----
__global__ __launch_bounds__(256) void norm_k(const bf16* __restrict__ lg,
                                              const float* __restrict__ rowM, const float* __restrict__ rowL,
                                              float* __restrict__ out){
  const int tid = threadIdx.x;
  const int row = blockIdx.x;
  const float M = rowM[row], inv = 1.f/rowL[row];
  const bf16* p = lg + (size_t)row*V_;
  float* q = out + (size_t)row*V_;
  for (int c = tid; c < V_/8; c += 256){
    union { s8v v; unsigned short us[8]; } u;
    u.v = *((const s8v*)p + c);
    f4 o0, o1;
    #pragma unroll
    for (int k = 0; k < 4; ++k) o0[k] = __expf(bfu2f(u.us[k]) - M)*inv;
    #pragma unroll
    for (int k = 0; k < 4; ++k) o1[k] = __expf(bfu2f(u.us[4+k]) - M)*inv;
    *((f4*)q + c*2)     = o0;
    *((f4*)q + c*2 + 1) = o1;
  }
}

// ---- init kernels ----
__global__ __launch_bounds__(256) void enc_init_k(const float* __restrict__ enc_init,
                                                  const float* __restrict__ bihf, const float* __restrict__ bihb,
                                                  bf16* __restrict__ hb0, float* __restrict__ hfE,
                                                  float* __restrict__ bias_fb){
  int i = blockIdx.x*256 + threadIdx.x;
  int base = i*8;
  int dir = base>>15, rem = base&32767, col = rem&1023;
  const float* sp = enc_init + dir*H_ + col;
  f4 a = *(const f4*)sp, b = *(const f4*)(sp+4);
  union { s8v v; bf16 h[8]; } o;
  #pragma unroll
  for (int k=0;k<4;k++){ o.h[k]=f2b(a[k]); o.h[4+k]=f2b(b[k]); }
  *(s8v*)(hb0 + dir*32768 + rem) = o.v;
  *(f4*)(hfE + dir*32768 + rem) = a;
  *(f4*)(hfE + dir*32768 + rem + 4) = b;
  if (i < 6144) bias_fb[i] = (i < 3072) ? bihf[i] : bihb[i-3072];
}
__global__ __launch_bounds__(256) void dec_init_k(const float* __restrict__ dinh,
                                                  bf16* __restrict__ hd0, float* __restrict__ hfD){
  int i = blockIdx.x*256 + threadIdx.x;
  int base = i*8;
  int col = base&1023;
  const float* sp = dinh + col;
  f4 a = *(const f4*)sp, b = *(const f4*)(sp+4);
  union { s8v v; bf16 h[8]; } o;
  #pragma unroll
  for (int k=0;k<4;k++){ o.h[k]=f2b(a[k]); o.h[4+k]=f2b(b[k]); }
  *(s8v*)(hd0 + base) = o.v;
  *(f4*)(hfD + base) = a;
  *(f4*)(hfD + base + 4) = b;
}

// ---- encoder: ONE STEP per launch, 64 blocks ----
__global__ __launch_bounds__(256) void enc_step_k(
  const float* __restrict__ gi_fb,
  const bf16* __restrict__ whhf, const bf16* __restrict__ whhb,
  const float* __restrict__ bhhf, const float* __restrict__ bhhb,
  const bf16* __restrict__ hrd_base, bf16* __restrict__ hwr_base,
  float* __restrict__ hfE, bf16* __restrict__ enc_out, int s)
{
  __shared__ bf16 hst[16][1032];
  __shared__ bf16 hsT[16][64];
  const int tid = threadIdx.x, bid = blockIdx.x;
  const int w = tid>>6, l = tid&63;
  const int lr = l&15, koff = (l>>4)*8, rb = (l>>4)*4;
  const int x = bid&7, g3 = bid>>3;
  const int dir = x>>2;
  const int mt = g3>>2;
  const int jtb = (x&3)*16 + (g3&3)*4;
  const int jt = jtb + w;
  const int col = jt*16 + lr;
  const bf16* W    = dir ? whhb : whhf;
  const float* bhh = dir ? bhhb : bhhf;
  const float br_ = bhh[col], bz_ = bhh[H_+col], bn_ = bhh[2*H_+col];
  const bf16* pr = W + (size_t)(jt*16 + lr)*H_ + koff;
  const bf16* pz = pr + (size_t)H_*H_;
  const bf16* pn = pz + (size_t)H_*H_;
  {
    const bf16* src = hrd_base + dir*32768 + (size_t)mt*16*H_;
    #pragma unroll
    for (int c = 0; c < 8; ++c){
      int g = c*256 + tid;
      int row = g>>7, off = g&127;
      *(s8v*)&hst[row][off*8] = *(const s8v*)(src + (size_t)row*H_ + off*8);
    }
  }
  __syncthreads();
  f4 accr = (f4){0,0,0,0}, accz = (f4){0,0,0,0}, accn = (f4){0,0,0,0};
  #pragma unroll 4
  for (int k0 = 0; k0 < H_; k0 += 32){
    s8v a = *(const s8v*)&hst[lr][koff + k0];
    accr = MFMA16(a, *(const s8v*)(pr + k0), accr);
    accz = MFMA16(a, *(const s8v*)(pz + k0), accz);
    accn = MFMA16(a, *(const s8v*)(pn + k0), accn);
  }
  const int es = dir ? (63 - s) : s;
  const int dcol = dir*3072 + col;
  #pragma unroll
  for (int ri = 0; ri < 4; ++ri){
    const int b_ = mt*16 + rb + ri;
    const size_t gr = (size_t)(es*B_ + b_)*6144;
    float ir = gi_fb[gr + dcol], iz = gi_fb[gr + 1024 + dcol], inn = gi_fb[gr + 2048 + dcol];
    float rg = fsigmoid(ir + accr[ri] + br_);
    float zg = fsigmoid(iz + accz[ri] + bz_);
    float ng = ftanh(inn + rg*(accn[ri] + bn_));
    float hold = hfE[dir*32768 + b_*H_ + col];
    float hnew = (1.f - zg)*ng + zg*hold;
    hfE[dir*32768 + b_*H_ + col] = hnew;
    hsT[rb+ri][w*16+lr] = f2b(hnew);
  }
  __syncthreads();
  {
    const int row = tid>>4, seg = tid&15;
    ull v = *(ull*)&hsT[row][seg*4];
    *(ull*)(hwr_base + dir*32768 + (size_t)(mt*16+row)*H_ + jtb*16 + seg*4) = v;
    *(ull*)(enc_out + (size_t)(es*B_ + mt*16+row)*2048 + dir*H_ + jtb*16 + seg*4) = v;
  }
}

// ---- decoder kA: 64 blocks.
// bid<16 (P): hmt=bid&1, x2=bid>>1 -> hW1 slice (16 b x 128 j) in LDS + partial scores sc8[x2]
// bid>=16 (G): gh = h@Whh^T + bhh (unchanged)
__global__ __launch_bounds__(256) void dec_kA(
  const bf16* __restrict__ hd,
  const bf16* __restrict__ whhd, const float* __restrict__ bhhd,
  const bf16* __restrict__ w1b,
  const bf16* __restrict__ encW1b,
  const float* __restrict__ attnW2,
  float* __restrict__ gh,
  float* __restrict__ sc8)            // [8][64][32] f32 partial scores
{
  __shared__ bf16 hst[16][1032];
  __shared__ float ghT[16][128];
  __shared__ float hwf2[4][16][33];   // [jg][b-local][j-in-group] (2-way banks max)
  __shared__ float scp[64][17];
  __shared__ float w2s2[4][33];
  const int tid = threadIdx.x, bid = blockIdx.x;
  const int w = tid>>6, l = tid&63;
  const int lr = l&15, koff = (l>>4)*8;
  const bool isP = bid < 16;
  const int hmt = isP ? (bid&1) : ((bid-16)&1);
  const int x2 = bid>>1;              // P only
  {
    const bf16* src = hd + (size_t)hmt*16*H_;
    #pragma unroll
    for (int c = 0; c < 8; ++c){
      int g = c*256 + tid;
      int row = g>>7, off = g&127;
      *(s8v*)&hst[row][off*8] = *(const s8v*)(src + (size_t)row*H_ + off*8);
    }
  }
  if (isP && tid < 128) w2s2[tid>>5][tid&31] = attnW2[x2*128 + tid];
  __syncthreads();
  if (isP){
    // hW1 slice: j-tiles pjt0..pjt0+1 per wave (128 j total for block)
    const int pjt0 = x2*8 + w*2;
    #pragma unroll
    for (int q = 0; q < 2; ++q){
      const bf16* pb = w1b + (size_t)((pjt0+q)*16 + lr)*H3_ + 2048 + koff;
      f4 acc = (f4){0,0,0,0};
      #pragma unroll 4
      for (int k0 = 0; k0 < H_; k0 += 32)
        acc = MFMA16(*(const s8v*)&hst[lr][koff+k0], *(const s8v*)(pb+k0), acc);
      const int jl = (w*2+q);         // local 16-tile index 0..7
      #pragma unroll
      for (int r = 0; r < 4; ++r)
        hwf2[jl>>1][(l>>4)*4+r][(jl&1)*16 + lr] = acc[r];
    }
    __syncthreads();
    // partial scores: lane owns (bl = l&15, jg = l>>4); wave w covers s = w*16..+16
    const int bl = l&15, jg = l>>4;
    const bf16* ebase = encW1b + ((size_t)(hmt*16 + bl))*H_ + x2*128 + jg*32;
    for (int si = 0; si < 16; ++si){
      const int s = w*16 + si;
      const bf16* ep = ebase + (size_t)s*B_*H_;
      float pp = 0.f;
      #pragma unroll
      for (int c8 = 0; c8 < 4; ++c8){
        union{ s8v v; unsigned short us[8]; } ev;
        ev.v = *(const s8v*)(ep + c8*8);
        #pragma unroll
        for (int k = 0; k < 8; ++k){
          const int jj = c8*8 + k;
          pp += w2s2[jg][jj]*ftanh(bfu2f(ev.us[k]) + hwf2[jg][bl][jj]);
        }
      }
      pp += __shfl_xor(pp, 16);
      pp += __shfl_xor(pp, 32);
      if (l < 16) scp[s][l] = pp;
    }
    __syncthreads();
    {
      const int s = tid>>2, v4 = tid&3;
      f4 o;
      o[0] = scp[s][v4*4];   o[1] = scp[s][v4*4+1];
      o[2] = scp[s][v4*4+2]; o[3] = scp[s][v4*4+3];
      *(f4*)(sc8 + (size_t)x2*2048 + s*32 + hmt*16 + v4*4) = o;
    }
  } else {
    const int gb = bid - 16;
    const int rest = gb>>1;
    const int x3 = rest/3, gkk = rest%3;
    const int ntb = x3*24 + gkk*8;
    #pragma unroll
    for (int q = 0; q < 2; ++q){
      const int nt = ntb + w*2 + q;
      const bf16* pb = whhd + (size_t)(nt*16 + lr)*H_ + koff;
      const float bv = bhhd[nt*16 + lr];
      f4 acc = (f4){0,0,0,0};
      #pragma unroll 4
      for (int k0 = 0; k0 < H_; k0 += 32)
        acc = MFMA16(*(const s8v*)&hst[lr][koff+k0], *(const s8v*)(pb+k0), acc);
      #pragma unroll
      for (int r = 0; r < 4; ++r)
        ghT[(l>>4)*4+r][(w*2+q)*16 + lr] = acc[r] + bv;
    }
    __syncthreads();
    #pragma unroll
    for (int i = 0; i < 4; ++i){
      int idx = tid + i*256;
      int row = idx>>6, seg = idx&63;
      union{ float f[2]; ull u; } pk;
      pk.f[0] = ghT[row][seg*2]; pk.f[1] = ghT[row][seg*2+1];
      *(ull*)(gh + (size_t)(hmt*16+row)*H3_ + ntb*16 + seg*2) = pk.u;
    }
  }
}

// ---- decoder kB: combine partial scores + softmax + glimpse + GRU. 128 blocks ----
__global__ __launch_bounds__(256) void dec_kB(
  const float* __restrict__ gi_t,
  const bf16* __restrict__ encWgb, const float* __restrict__ gh,
  const float* __restrict__ sc8,
  float* __restrict__ hfD, bf16* __restrict__ hd_w, bf16* __restrict__ hall_t)
{
  __shared__ float scc2[64][33];
  __shared__ float watst[64];
  __shared__ float part_[4][3][256];
  __shared__ bf16 hnewst[256];
  const int tid = threadIdx.x, bid = blockIdx.x;
  const int x = bid&7, g3 = bid>>3;
  const int db = 4*x + (g3&3), jq = g3>>2;
  const int jD = jq*256 + tid;
  // combine 8 partial-score slices
  {
    const int base = tid*8, s = base>>5, b0 = base&31;
    f4 a0 = (f4){0,0,0,0}, a1 = (f4){0,0,0,0};
    #pragma unroll
    for (int x2 = 0; x2 < 8; ++x2){
      a0 += *(const f4*)(sc8 + (size_t)x2*2048 + base);
      a1 += *(const f4*)(sc8 + (size_t)x2*2048 + base + 4);
    }
    #pragma unroll
    for (int k = 0; k < 4; ++k){ scc2[s][b0+k] = a0[k]; scc2[s][b0+4+k] = a1[k]; }
  }
  __syncthreads();
  if (tid < 64){
    const int s = tid;
    float m = -1e30f;
    #pragma unroll 8
    for (int b = 0; b < 32; ++b) m = fmaxf(m, scc2[s][b]);
    float Z = 0.f;
    #pragma unroll 8
    for (int b = 0; b < 32; ++b) Z += __expf(scc2[s][b] - m);
    watst[s] = __expf(scc2[s][db] - m)/Z;
  }
  __syncthreads();
  const int lane = tid&63, wv = tid>>6;
  const int j0 = jq*256 + lane*4;
  f4 g0 = (f4){0,0,0,0}, g1 = (f4){0,0,0,0}, g2 = (f4){0,0,0,0};
  #pragma unroll 4
  for (int i = 0; i < 16; ++i){
    const int s2 = wv*16 + i;
    const float wt = watst[s2];
    const bf16* ro = encWgb + ((size_t)s2*B_ + db)*H3_;
    union{ ull u; unsigned short us[4]; } v0, v1, v2;
    v0.u = *(const ull*)(ro + j0);
    v1.u = *(const ull*)(ro + H_ + j0);
    v2.u = *(const ull*)(ro + 2*H_ + j0);
    #pragma unroll
    for (int k = 0; k < 4; ++k){
      g0[k] += wt*bfu2f(v0.us[k]);
      g1[k] += wt*bfu2f(v1.us[k]);
      g2[k] += wt*bfu2f(v2.us[k]);
    }
  }
  *(f4*)&part_[wv][0][lane*4] = g0;
  *(f4*)&part_[wv][1][lane*4] = g1;
  *(f4*)&part_[wv][2][lane*4] = g2;
  __syncthreads();
  float G0 = part_[0][0][tid]+part_[1][0][tid]+part_[2][0][tid]+part_[3][0][tid];
  float G1 = part_[0][1][tid]+part_[1][1][tid]+part_[2][1][tid]+part_[3][1][tid];
  float G2 = part_[0][2][tid]+part_[1][2][tid]+part_[2][2][tid]+part_[3][2][tid];
  const float* gp = gi_t + (size_t)db*H3_ + jD;
  float ir  = gp[0]    + G0;
  float iz  = gp[H_]   + G1;
  float inn = gp[2*H_] + G2;
  float hr_ = gh[(size_t)db*H3_ + jD];
  float hz_ = gh[(size_t)db*H3_ + H_ + jD];
  float hn_ = gh[(size_t)db*H3_ + 2*H_ + jD];
  float rg = fsigmoid(ir + hr_);
  float zg = fsigmoid(iz + hz_);
  float ng = ftanh(inn + rg*hn_);
  float hold = hfD[(size_t)db*H_ + jD];
  float hnew = (1.f - zg)*ng + zg*hold;
  hfD[(size_t)db*H_ + jD] = hnew;
  hnewst[tid] = f2b(hnew);
  __syncthreads();
  if (tid < 64){
    ull v = *(ull*)&hnewst[tid*4];
    *(ull*)(hd_w + (size_t)db*H_ + jq*256 + tid*4) = v;
    *(ull*)(hall_t + (size_t)db*H_ + jq*256 + tid*4) = v;
  }
}

extern "C" void kernel_launch(void* const* d_in, const int* in_sizes, int n_in,
                              void* d_out, int out_size, void* d_ws, size_t ws_size,
                              hipStream_t stream)
{
  (void)in_sizes; (void)n_in; (void)out_size; (void)ws_size;
  const int*   iseq  = (const int*)d_in[0];
  const int*   tseq  = (const int*)d_in[1];
  const float* emb   = (const float*)d_in[2];
  const float* wihf  = (const float*)d_in[3];
  const float* whhf_f= (const float*)d_in[4];
  const float* bihf  = (const float*)d_in[5];
  const float* bhhf  = (const float*)d_in[6];
  const float* wihb  = (const float*)d_in[7];
  const float* whhb_f= (const float*)d_in[8];
  const float* bihb  = (const float*)d_in[9];
  const float* bhhb  = (const float*)d_in[10];
  const float* einit = (const float*)d_in[11];
  const float* wihd  = (const float*)d_in[12];
  const float* whhd_f= (const float*)d_in[13];
  const float* bihd  = (const float*)d_in[14];
  const float* bhhd  = (const float*)d_in[15];
  const float* dinh  = (const float*)d_in[16];
  const float* dino  = (const float*)d_in[17];
  const float* w1    = (const float*)d_in[18];
  const float* w2    = (const float*)d_in[19];
  const float* outw  = (const float*)d_in[20];
  const float* outb  = (const float*)d_in[21];
  float* out = (float*)d_out;

  char* ws = (char*)d_ws;
  size_t off = 0;
  auto alloc = [&](size_t bytes)->char*{ char* p = ws + off; off += (bytes + 255) & ~(size_t)255; return p; };
  // ---- FRONT POOL: all dead before the output stage; logits_b (131.07 MB) aliases it ----
  bf16* logits_b = (bf16*)ws;                              // [2048][32000] bf16
  bf16* x_b      = (bf16*)alloc((size_t)2048*512*2);
  bf16* lo_b     = (bf16*)alloc((size_t)2048*512*2);
  bf16* wihf_b   = (bf16*)alloc((size_t)3072*512*2);
  bf16* wihb_b   = (bf16*)alloc((size_t)3072*512*2);
  bf16* whhf_b   = (bf16*)alloc((size_t)3072*1024*2);
  bf16* whhb_b   = (bf16*)alloc((size_t)3072*1024*2);
  bf16* wihd_b   = (bf16*)alloc((size_t)3072*3072*2);
  bf16* whhd_b   = (bf16*)alloc((size_t)3072*1024*2);
  bf16* w1_b     = (bf16*)alloc((size_t)1024*3072*2);
  float* gi_fb   = (float*)alloc((size_t)2048*6144*4);
  float* gi_d    = (float*)alloc((size_t)2048*3072*4);
  bf16* enc_b    = (bf16*)alloc((size_t)2048*2048*2);      // front pool ends ≥131.07 MB here
  // ---- persistent-small + tail (NOT aliased) ----
  bf16* encW1_b  = (bf16*)alloc((size_t)2048*1024*2);
  bf16* encWg_b  = (bf16*)alloc((size_t)2048*3072*2);
  float* bias_fb = (float*)alloc((size_t)6144*4);
  bf16*  henc_b  = (bf16*)alloc((size_t)2*65536*2);
  float* hfE     = (float*)alloc((size_t)2*32768*4);
  bf16*  hdb     = (bf16*)alloc((size_t)2*32768*2);
  float* hfD     = (float*)alloc((size_t)32768*4);
  float* ghb     = (float*)alloc((size_t)32*3072*4);
  float* sc8     = (float*)alloc((size_t)8*64*32*4);
  float* rowM    = (float*)alloc((size_t)2048*4);
  float* rowL    = (float*)alloc((size_t)2048*4);
  bf16* outw_b   = (bf16*)alloc((size_t)32000*1024*2);
  bf16*  hall_b  = (bf16*)alloc((size_t)2048*1024*2);

  gather2_k<<<dim3(512,2), 256, 0, stream>>>(emb, iseq, tseq, dino, x_b, lo_b);
  cast2_k<<<dim3(768,2),  256, 0, stream>>>(wihf, wihb, wihf_b, wihb_b, 196608);
  cast4_k<<<dim3(768,4),  256, 0, stream>>>(whhf_f, whhb_f, whhd_f, w1,
                                            whhf_b, whhb_b, whhd_b, w1_b, 393216);
  cast_bf16_k<<<2048, 256, 0, stream>>>(wihd, wihd_b, 1179648);
  cast_bf16_k<<<2048, 256, 0, stream>>>(outw, outw_b, 4096000);
  enc_init_k<<<32, 256, 0, stream>>>(einit, bihf, bihb, henc_b, hfE, bias_fb);

  gemm_bt<0,0><<<dim3(48,16), 256, 0, stream>>>(x_b, 512, wihf_b,      512,  bias_fb, gi_fb, 6144, 512);
  gemm_bt<0,0><<<dim3(24,16), 256, 0, stream>>>(x_b, 512, wihd_b,      3072, bihd,    gi_d,  3072, 512);
  gemm_bt<0,1><<<dim3(24,16), 256, 0, stream>>>(lo_b,512, wihd_b+2560, 3072, nullptr, gi_d,  3072, 512);

  for (int s = 0; s < 64; ++s){
    const bf16* hrd = henc_b + (size_t)(s&1)*65536;
    bf16*       hwr = henc_b + (size_t)((s+1)&1)*65536;
    enc_step_k<<<64, 256, 0, stream>>>(gi_fb, whhf_b, whhb_b, bhhf, bhhb,
                                       hrd, hwr, hfE, enc_b, s);
  }

  gemm_bt<1,0><<<dim3(8,16),  256, 0, stream>>>(enc_b, 2048, w1_b,       3072, nullptr, encW1_b, 1024, 2048);
  gemm_bt<1,0><<<dim3(24,16), 256, 0, stream>>>(enc_b, 2048, wihd_b+512, 3072, nullptr, encWg_b, 3072, 2048);

  dec_init_k<<<16, 256, 0, stream>>>(dinh, hdb, hfD);
  for (int t = 0; t < 64; ++t){
    const bf16* hdr = hdb + (size_t)(t&1)*32768;
    bf16*       hdw = hdb + (size_t)((t+1)&1)*32768;
    dec_kA<<<64, 256, 0, stream>>>(hdr, whhd_b, bhhd, w1_b, encW1_b, w2, ghb, sc8);
    dec_kB<<<128, 256, 0, stream>>>(gi_d + (size_t)t*B_*H3_, encWg_b, ghb, sc8,
                                    hfD, hdw, hall_b + (size_t)t*B_*H_);
  }

  out_gemm_k<<<4096, 256, 0, stream>>>(hall_b, outw_b, outb, logits_b);
  logit_stats_k<<<2048, 256, 0, stream>>>(logits_b, rowM, rowL);
  norm_k<<<2048, 256, 0, stream>>>(logits_b, rowM, rowL, out);
}

// Round 12
// 3080.037 us; speedup vs baseline: 1.3966x; 1.3966x over previous
//
#include <hip/hip_runtime.h>
#include <hip/hip_bf16.h>

#define S_ 64
#define B_ 32
#define V_ 32000
#define E_ 512
#define H_ 1024
#define H3_ 3072

typedef __hip_bfloat16 bf16;
typedef __attribute__((ext_vector_type(8))) short s8v;
typedef __attribute__((ext_vector_type(4))) float f4;
typedef unsigned long long ull;

__device__ __forceinline__ float b2f(bf16 x){ return __bfloat162float(x); }
__device__ __forceinline__ bf16  f2b(float x){ return __float2bfloat16(x); }
__device__ __forceinline__ float bfu2f(unsigned short u){
  union { unsigned u; float f; } c; c.u = ((unsigned)u) << 16; return c.f;
}
#define MFMA16(a,b,c) __builtin_amdgcn_mfma_f32_16x16x32_bf16((a),(b),(c),0,0,0)

__device__ __forceinline__ float fsigmoid(float x){ return 1.f/(1.f + __expf(-x)); }
__device__ __forceinline__ float ftanh(float x){ float e2 = __expf(2.f*x); return 1.f - 2.f/(e2 + 1.f); }

// async global->LDS, 16B per lane; LDS base must be wave-uniform, dest = base + lane*16
__device__ __forceinline__ void gl16(const bf16* g, bf16* l){
  __builtin_amdgcn_global_load_lds((const __attribute__((address_space(1))) void*)g,
                                   (__attribute__((address_space(3))) void*)l, 16, 0, 0);
}

__device__ __forceinline__ void cast8(const float* __restrict__ s, bf16* __restrict__ d, int i){
  f4 a = *((const f4*)s + (size_t)i*2);
  f4 b = *((const f4*)s + (size_t)i*2 + 1);
  union { s8v v; bf16 h[8]; } o;
  #pragma unroll
  for (int k=0;k<4;k++){ o.h[k]=f2b(a[k]); o.h[4+k]=f2b(b[k]); }
  *((s8v*)d + i) = o.v;
}

// ---- merged prep: all casts + gathers + inits in one launch ----
__global__ __launch_bounds__(256) void prep_all_k(
  const float* __restrict__ emb, const int* __restrict__ iseq, const int* __restrict__ tseq,
  const float* __restrict__ dino,
  const float* __restrict__ wihf, const float* __restrict__ wihb,
  const float* __restrict__ whhf, const float* __restrict__ whhb,
  const float* __restrict__ whhd, const float* __restrict__ w1,
  const float* __restrict__ wihd, const float* __restrict__ outw,
  const float* __restrict__ einit, const float* __restrict__ bihf,
  const float* __restrict__ bihb, const float* __restrict__ dinh,
  bf16* __restrict__ x_b, bf16* __restrict__ lo_b,
  bf16* __restrict__ wihf_b, bf16* __restrict__ wihb_b,
  bf16* __restrict__ whhf_b, bf16* __restrict__ whhb_b,
  bf16* __restrict__ whhd_b, bf16* __restrict__ w1_b,
  bf16* __restrict__ wihd_b, bf16* __restrict__ outw_b,
  bf16* __restrict__ henc_b, float* __restrict__ hfE, float* __restrict__ bias_fb,
  bf16* __restrict__ hdb, float* __restrict__ hfD)
{
  const int task = blockIdx.y;
  const int stride = gridDim.x*256;
  const int i00 = blockIdx.x*256 + threadIdx.x;
  if (task < 8){
    const float* s; bf16* d; int n8;
    switch(task){
      case 0: s=wihf; d=wihf_b; n8=196608; break;    // 3072*512/8
      case 1: s=wihb; d=wihb_b; n8=196608; break;
      case 2: s=whhf; d=whhf_b; n8=393216; break;    // 3072*1024/8
      case 3: s=whhb; d=whhb_b; n8=393216; break;
      case 4: s=whhd; d=whhd_b; n8=393216; break;
      case 5: s=w1;   d=w1_b;   n8=393216; break;    // 1024*3072/8
      case 6: s=wihd; d=wihd_b; n8=1179648; break;   // 3072*3072/8
      default: s=outw; d=outw_b; n8=4096000; break;  // 32000*1024/8
    }
    for (int i = i00; i < n8; i += stride) cast8(s, d, i);
  } else if (task == 8 || task == 9){
    for (int i = i00; i < 131072; i += stride){
      int row = i>>6, e8 = i&63;
      const float* src; bf16* d;
      if (task == 8){ src = emb + (size_t)iseq[row]*E_; d = x_b; }
      else {
        int t = row>>5, b = row&31;
        src = (t == 0) ? dino : (emb + (size_t)tseq[(t-1)*B_ + b]*E_);
        d = lo_b;
      }
      f4 a = *((const f4*)src + e8*2);
      f4 b = *((const f4*)src + e8*2 + 1);
      union { s8v v; bf16 h[8]; } o;
      #pragma unroll
      for (int k=0;k<4;k++){ o.h[k]=f2b(a[k]); o.h[4+k]=f2b(b[k]); }
      *((s8v*)d + i) = o.v;
    }
  } else if (task == 10){
    for (int i = i00; i < 8192; i += stride){
      int base = i*8;
      int dir = base>>15, rem = base&32767, col = rem&1023;
      const float* sp = einit + dir*H_ + col;
      f4 a = *(const f4*)sp, b = *(const f4*)(sp+4);
      union { s8v v; bf16 h[8]; } o;
      #pragma unroll
      for (int k=0;k<4;k++){ o.h[k]=f2b(a[k]); o.h[4+k]=f2b(b[k]); }
      *(s8v*)(henc_b + dir*32768 + rem) = o.v;
      *(f4*)(hfE + dir*32768 + rem) = a;
      *(f4*)(hfE + dir*32768 + rem + 4) = b;
      if (i < 6144) bias_fb[i] = (i < 3072) ? bihf[i] : bihb[i-3072];
    }
  } else {
    for (int i = i00; i < 4096; i += stride){
      int base = i*8;
      int col = base&1023;
      const float* sp = dinh + col;
      f4 a = *(const f4*)sp, b = *(const f4*)(sp+4);
      union { s8v v; bf16 h[8]; } o;
      #pragma unroll
      for (int k=0;k<4;k++){ o.h[k]=f2b(a[k]); o.h[4+k]=f2b(b[k]); }
      *(s8v*)(hdb + base) = o.v;
      *(f4*)(hfD + base) = a;
      *(f4*)(hfD + base + 4) = b;
    }
  }
}

// ---- generic bf16 MFMA GEMM with global_load_lds staging ----
template<int WB16>
__global__ __launch_bounds__(256) void gemm_bt(const bf16* __restrict__ A, int lda,
                                               const bf16* __restrict__ B, int ldb,
                                               const float* __restrict__ bias,
                                               void* __restrict__ Cp, int ldc, int K)
{
  __shared__ bf16 a_sm[128][32];
  __shared__ bf16 b_sm[128][32];
  const int tid = threadIdx.x;
  const int m0 = blockIdx.y*128, n0 = blockIdx.x*128;
  const int w = tid>>6, l = tid&63;
  const int wm = w>>1, wn = w&1;
  f4 acc[4][4];
  #pragma unroll
  for (int i=0;i<4;i++)
    #pragma unroll
    for (int j=0;j<4;j++) acc[i][j] = (f4){0.f,0.f,0.f,0.f};
  const int ar = l&15, koff = (l>>4)*8;
  const int glr = l>>2, gls = (l&3)*8;
  for (int k0 = 0; k0 < K; k0 += 32){
    __syncthreads();
    #pragma unroll
    for (int o = 0; o < 2; ++o){
      const int oo = w*2 + o;
      gl16(A + (size_t)(m0 + oo*16 + glr)*lda + k0 + gls, &a_sm[oo*16][0]);
      gl16(B + (size_t)(n0 + oo*16 + glr)*ldb + k0 + gls, &b_sm[oo*16][0]);
    }
    __syncthreads();
    s8v av[4], bv[4];
    #pragma unroll
    for (int i=0;i<4;i++) av[i] = *(const s8v*)&a_sm[wm*64 + i*16 + ar][koff];
    #pragma unroll
    for (int j=0;j<4;j++) bv[j] = *(const s8v*)&b_sm[wn*64 + j*16 + ar][koff];
    #pragma unroll
    for (int i=0;i<4;i++)
      #pragma unroll
      for (int j=0;j<4;j++)
        acc[i][j] = MFMA16(av[i], bv[j], acc[i][j]);
  }
  const int rb = (l>>4)*4;
  #pragma unroll
  for (int i=0;i<4;i++){
    #pragma unroll
    for (int j=0;j<4;j++){
      int col = n0 + wn*64 + j*16 + ar;
      float badd = bias ? bias[col] : 0.f;
      #pragma unroll
      for (int r=0;r<4;r++){
        int row = m0 + wm*64 + i*16 + rb + r;
        size_t idx = (size_t)row*ldc + col;
        float v = acc[i][j][r] + badd;
        if (WB16) ((bf16*)Cp)[idx] = f2b(v);
        else      ((float*)Cp)[idx] = v;
      }
    }
  }
}

// ---- dual-phase GEMM for gi_d: C = A1·Bw[:, :512]^T + A2·Bw[:,2560:]^T + bias ----
__global__ __launch_bounds__(256) void gemm_dual(const bf16* __restrict__ A1, const bf16* __restrict__ A2,
                                                 const bf16* __restrict__ Bw, const float* __restrict__ bias,
                                                 float* __restrict__ C)
{
  __shared__ bf16 a_sm[128][32];
  __shared__ bf16 b_sm[128][32];
  const int tid = threadIdx.x;
  const int m0 = blockIdx.y*128, n0 = blockIdx.x*128;
  const int w = tid>>6, l = tid&63;
  const int wm = w>>1, wn = w&1;
  f4 acc[4][4];
  #pragma unroll
  for (int i=0;i<4;i++)
    #pragma unroll
    for (int j=0;j<4;j++) acc[i][j] = (f4){0.f,0.f,0.f,0.f};
  const int ar = l&15, koff = (l>>4)*8;
  const int glr = l>>2, gls = (l&3)*8;
  #pragma unroll 1
  for (int p = 0; p < 2; ++p){
    const bf16* Ax = p ? A2 : A1;
    const int cb = p ? 2560 : 0;
    for (int k0 = 0; k0 < 512; k0 += 32){
      __syncthreads();
      #pragma unroll
      for (int o = 0; o < 2; ++o){
        const int oo = w*2 + o;
        gl16(Ax + (size_t)(m0 + oo*16 + glr)*512 + k0 + gls, &a_sm[oo*16][0]);
        gl16(Bw + (size_t)(n0 + oo*16 + glr)*3072 + cb + k0 + gls, &b_sm[oo*16][0]);
      }
      __syncthreads();
      s8v av[4], bv[4];
      #pragma unroll
      for (int i=0;i<4;i++) av[i] = *(const s8v*)&a_sm[wm*64 + i*16 + ar][koff];
      #pragma unroll
      for (int j=0;j<4;j++) bv[j] = *(const s8v*)&b_sm[wn*64 + j*16 + ar][koff];
      #pragma unroll
      for (int i=0;i<4;i++)
        #pragma unroll
        for (int j=0;j<4;j++)
          acc[i][j] = MFMA16(av[i], bv[j], acc[i][j]);
    }
  }
  const int rb = (l>>4)*4;
  #pragma unroll
  for (int i=0;i<4;i++){
    #pragma unroll
    for (int j=0;j<4;j++){
      int col = n0 + wn*64 + j*16 + ar;
      float badd = bias[col];
      #pragma unroll
      for (int r=0;r<4;r++){
        int row = m0 + wm*64 + i*16 + rb + r;
        C[(size_t)row*H3_ + col] = acc[i][j][r] + badd;
      }
    }
  }
}

// ---- output-projection GEMM: XCD-supertile swizzle + gl16 staging, bf16 logits out ----
__global__ __launch_bounds__(256) void out_gemm_k(
  const bf16* __restrict__ A, const bf16* __restrict__ Bw,
  const float* __restrict__ bias, bf16* __restrict__ C)
{
  __shared__ bf16 a_sm[128][32];
  __shared__ bf16 b_sm[128][32];
  const int tid = threadIdx.x;
  const int bid = blockIdx.x;
  const int xcd = bid & 7, kk = bid >> 3;
  const int super = kk >> 6, rem = kk & 63;
  const int sm = super & 1, sn = super >> 1;
  const int mi = rem & 7, nj = rem >> 3;
  const int mt = sm*8 + mi, nl = sn*8 + nj;
  const int nt = nl*8 + xcd;
  if (nt >= 250) return;
  const int m0 = mt*128, n0 = nt*128;
  const int w = tid>>6, l = tid&63;
  const int wm = w>>1, wn = w&1;
  f4 acc[4][4];
  #pragma unroll
  for (int i=0;i<4;i++)
    #pragma unroll
    for (int j=0;j<4;j++) acc[i][j] = (f4){0.f,0.f,0.f,0.f};
  const int ar = l&15, koff = (l>>4)*8;
  const int glr = l>>2, gls = (l&3)*8;
  for (int k0 = 0; k0 < 1024; k0 += 32){
    __syncthreads();
    #pragma unroll
    for (int o = 0; o < 2; ++o){
      const int oo = w*2 + o;
      gl16(A + (size_t)(m0 + oo*16 + glr)*1024 + k0 + gls, &a_sm[oo*16][0]);
      gl16(Bw + (size_t)(n0 + oo*16 + glr)*1024 + k0 + gls, &b_sm[oo*16][0]);
    }
    __syncthreads();
    s8v av[4], bv[4];
    #pragma unroll
    for (int i=0;i<4;i++) av[i] = *(const s8v*)&a_sm[wm*64 + i*16 + ar][koff];
    #pragma unroll
    for (int j=0;j<4;j++) bv[j] = *(const s8v*)&b_sm[wn*64 + j*16 + ar][koff];
    #pragma unroll
    for (int i=0;i<4;i++)
      #pragma unroll
      for (int j=0;j<4;j++)
        acc[i][j] = MFMA16(av[i], bv[j], acc[i][j]);
  }
  const int rb = (l>>4)*4;
  float bj[4];
  #pragma unroll
  for (int j=0;j<4;j++) bj[j] = bias[n0 + wn*64 + j*16 + ar];
  #pragma unroll
  for (int i=0;i<4;i++){
    #pragma unroll
    for (int j=0;j<4;j++){
      const int col = n0 + wn*64 + j*16 + ar;
      #pragma unroll
      for (int r=0;r<4;r++){
        const int row = m0 + wm*64 + i*16 + rb + r;
        C[(size_t)row*V_ + col] = f2b(acc[i][j][r] + bj[j]);
      }
    }
  }
}

// ---- logit stats: per-row max + sumexp from bf16 logits ----
__global__ __launch_bounds__(256) void logit_stats_k(const bf16* __restrict__ lg,
                                                     float* __restrict__ rowM, float* __restrict__ rowL){
  __shared__ float wm[4], wl[4];
  const int tid = threadIdx.x;
  const bf16* p = lg + (size_t)blockIdx.x*V_;
  float m = -1e30f, lsum = 0.f;
  for (int c = tid; c < V_/8; c += 256){
    union { s8v v; unsigned short us[8]; } u;
    u.v = *((const s8v*)p + c);
    #pragma unroll
    for (int k = 0; k < 8; ++k){
      float v = bfu2f(u.us[k]);
      float mn = fmaxf(m, v);
      lsum = lsum*__expf(m - mn) + __expf(v - mn);
      m = mn;
    }
  }
  #pragma unroll
  for (int o = 32; o; o >>= 1){
    float mo = __shfl_xor(m, o), lo_ = __shfl_xor(lsum, o);
    float mn = fmaxf(m, mo);
    lsum = lsum*__expf(m - mn) + lo_*__expf(mo - mn);
    m = mn;
  }
  if ((tid&63)==0){ wm[tid>>6] = m; wl[tid>>6] = lsum; }
  __syncthreads();
  if (tid == 0){
    float M = fmaxf(fmaxf(wm[0],wm[1]), fmaxf(wm[2],wm[3]));
    float L = wl[0]*__expf(wm[0]-M) + wl[1]*__expf(wm[1]-M)
            + wl[2]*__expf(wm[2]-M) + wl[3]*__expf(wm[3]-M);
    rowM[blockIdx.x] = M;
    rowL[blockIdx.x] = L;
  }
}

// ---- normalize: probs f32 from bf16 logits ----
__global__ __launch_bounds__(256) void norm_k(const bf16* __restrict__ lg,
                                              const float* __restrict__ rowM, const float* __restrict__ rowL,
                                              float* __restrict__ out){
  const int tid = threadIdx.x;
  const int row = blockIdx.x;
  const float M = rowM[row], inv = 1.f/rowL[row];
  const bf16* p = lg + (size_t)row*V_;
  float* q = out + (size_t)row*V_;
  for (int c = tid; c < V_/8; c += 256){
    union { s8v v; unsigned short us[8]; } u;
    u.v = *((const s8v*)p + c);
    f4 o0, o1;
    #pragma unroll
    for (int k = 0; k < 4; ++k) o0[k] = __expf(bfu2f(u.us[k]) - M)*inv;
    #pragma unroll
    for (int k = 0; k < 4; ++k) o1[k] = __expf(bfu2f(u.us[4+k]) - M)*inv;
    *((f4*)q + c*2)     = o0;
    *((f4*)q + c*2 + 1) = o1;
  }
}

// ---- encoder: ONE STEP per launch, 64 blocks ----
__global__ __launch_bounds__(256) void enc_step_k(
  const float* __restrict__ gi_fb,
  const bf16* __restrict__ whhf, const bf16* __restrict__ whhb,
  const float* __restrict__ bhhf, const float* __restrict__ bhhb,
  const bf16* __restrict__ hrd_base, bf16* __restrict__ hwr_base,
  float* __restrict__ hfE, bf16* __restrict__ enc_out, int s)
{
  __shared__ bf16 hst[16][1032];
  __shared__ bf16 hsT[16][64];
  const int tid = threadIdx.x, bid = blockIdx.x;
  const int w = tid>>6, l = tid&63;
  const int lr = l&15, koff = (l>>4)*8, rb = (l>>4)*4;
  const int x = bid&7, g3 = bid>>3;
  const int dir = x>>2;
  const int mt = g3>>2;
  const int jtb = (x&3)*16 + (g3&3)*4;
  const int jt = jtb + w;
  const int col = jt*16 + lr;
  const bf16* W    = dir ? whhb : whhf;
  const float* bhh = dir ? bhhb : bhhf;
  const float br_ = bhh[col], bz_ = bhh[H_+col], bn_ = bhh[2*H_+col];
  const bf16* pr = W + (size_t)(jt*16 + lr)*H_ + koff;
  const bf16* pz = pr + (size_t)H_*H_;
  const bf16* pn = pz + (size_t)H_*H_;
  {
    const bf16* src = hrd_base + dir*32768 + (size_t)mt*16*H_;
    #pragma unroll
    for (int c = 0; c < 8; ++c){
      int g = c*256 + tid;
      int row = g>>7, off = g&127;
      *(s8v*)&hst[row][off*8] = *(const s8v*)(src + (size_t)row*H_ + off*8);
    }
  }
  __syncthreads();
  f4 accr = (f4){0,0,0,0}, accz = (f4){0,0,0,0}, accn = (f4){0,0,0,0};
  #pragma unroll 4
  for (int k0 = 0; k0 < H_; k0 += 32){
    s8v a = *(const s8v*)&hst[lr][koff + k0];
    accr = MFMA16(a, *(const s8v*)(pr + k0), accr);
    accz = MFMA16(a, *(const s8v*)(pz + k0), accz);
    accn = MFMA16(a, *(const s8v*)(pn + k0), accn);
  }
  const int es = dir ? (63 - s) : s;
  const int dcol = dir*3072 + col;
  #pragma unroll
  for (int ri = 0; ri < 4; ++ri){
    const int b_ = mt*16 + rb + ri;
    const size_t gr = (size_t)(es*B_ + b_)*6144;
    float ir = gi_fb[gr + dcol], iz = gi_fb[gr + 1024 + dcol], inn = gi_fb[gr + 2048 + dcol];
    float rg = fsigmoid(ir + accr[ri] + br_);
    float zg = fsigmoid(iz + accz[ri] + bz_);
    float ng = ftanh(inn + rg*(accn[ri] + bn_));
    float hold = hfE[dir*32768 + b_*H_ + col];
    float hnew = (1.f - zg)*ng + zg*hold;
    hfE[dir*32768 + b_*H_ + col] = hnew;
    hsT[rb+ri][w*16+lr] = f2b(hnew);
  }
  __syncthreads();
  {
    const int row = tid>>4, seg = tid&15;
    ull v = *(ull*)&hsT[row][seg*4];
    *(ull*)(hwr_base + dir*32768 + (size_t)(mt*16+row)*H_ + jtb*16 + seg*4) = v;
    *(ull*)(enc_out + (size_t)(es*B_ + mt*16+row)*2048 + dir*H_ + jtb*16 + seg*4) = v;
  }
}

// ---- decoder k1: gh = h@Whh^T + bhh  AND  hW1 = h@W1h^T.  64 blocks ----
__global__ __launch_bounds__(256) void dec_k1(
  const bf16* __restrict__ hd,
  const bf16* __restrict__ whhd, const float* __restrict__ bhhd,
  const bf16* __restrict__ w1b,
  float* __restrict__ gh, bf16* __restrict__ hW1b)
{
  __shared__ bf16 hst[16][1032];
  __shared__ float ghT[16][128];
  __shared__ bf16 hwT[16][128];
  const int tid = threadIdx.x, bid = blockIdx.x;
  const int w = tid>>6, l = tid&63;
  const int lr = l&15, koff = (l>>4)*8;
  const bool isP = bid < 16;
  const int hmt = isP ? (bid&1) : ((bid-16)&1);
  {
    const bf16* src = hd + (size_t)hmt*16*H_;
    #pragma unroll
    for (int c = 0; c < 8; ++c){
      int g = c*256 + tid;
      int row = g>>7, off = g&127;
      *(s8v*)&hst[row][off*8] = *(const s8v*)(src + (size_t)row*H_ + off*8);
    }
  }
  __syncthreads();
  if (isP){
    const int x2 = bid>>1;
    const int pjt0 = x2*8 + w*2;
    #pragma unroll
    for (int q = 0; q < 2; ++q){
      const bf16* pb = w1b + (size_t)((pjt0+q)*16 + lr)*H3_ + 2048 + koff;
      f4 acc = (f4){0,0,0,0};
      #pragma unroll 4
      for (int k0 = 0; k0 < H_; k0 += 32)
        acc = MFMA16(*(const s8v*)&hst[lr][koff+k0], *(const s8v*)(pb+k0), acc);
      #pragma unroll
      for (int r = 0; r < 4; ++r)
        hwT[(l>>4)*4+r][(w*2+q)*16 + lr] = f2b(acc[r]);
    }
    __syncthreads();
    #pragma unroll
    for (int i = 0; i < 2; ++i){
      int idx = tid + i*256;
      int row = idx>>5, seg = idx&31;
      *(ull*)(hW1b + (size_t)(hmt*16+row)*H_ + x2*128 + seg*4) = *(ull*)&hwT[row][seg*4];
    }
  } else {
    const int gb = bid - 16;
    const int rest = gb>>1;
    const int x3 = rest/3, gkk = rest%3;
    const int ntb = x3*24 + gkk*8;
    #pragma unroll
    for (int q = 0; q < 2; ++q){
      const int nt = ntb + w*2 + q;
      const bf16* pb = whhd + (size_t)(nt*16 + lr)*H_ + koff;
      const float bv = bhhd[nt*16 + lr];
      f4 acc = (f4){0,0,0,0};
      #pragma unroll 4
      for (int k0 = 0; k0 < H_; k0 += 32)
        acc = MFMA16(*(const s8v*)&hst[lr][koff+k0], *(const s8v*)(pb+k0), acc);
      #pragma unroll
      for (int r = 0; r < 4; ++r)
        ghT[(l>>4)*4+r][(w*2+q)*16 + lr] = acc[r] + bv;
    }
    __syncthreads();
    #pragma unroll
    for (int i = 0; i < 4; ++i){
      int idx = tid + i*256;
      int row = idx>>6, seg = idx&63;
      union{ float f[2]; ull u; } pk;
      pk.f[0] = ghT[row][seg*2]; pk.f[1] = ghT[row][seg*2+1];
      *(ull*)(gh + (size_t)(hmt*16+row)*H3_ + ntb*16 + seg*2) = pk.u;
    }
  }
}

// ---- decoder k2: scores + softmax over batch. 64 blocks (one per s) ----
__global__ __launch_bounds__(256) void dec_k2(
  const bf16* __restrict__ encW1b, const bf16* __restrict__ hW1b,
  const float* __restrict__ attnW2, float* __restrict__ wat)
{
  __shared__ float w2st[1024];
  __shared__ float scl[32];
  const int tid = threadIdx.x, s = blockIdx.x;
  w2st[tid] = attnW2[tid];
  w2st[tid+256] = attnW2[tid+256];
  w2st[tid+512] = attnW2[tid+512];
  w2st[tid+768] = attnW2[tid+768];
  __syncthreads();
  const int b = tid>>3, part = tid&7;
  const bf16* hp = hW1b + (size_t)b*H_ + part*128;
  const bf16* ep = encW1b + ((size_t)s*B_ + b)*H_ + part*128;
  const float* wp = w2st + part*128;
  float p = 0.f;
  #pragma unroll 4
  for (int ii = 0; ii < 16; ++ii){
    union { s8v v; unsigned short uu[8]; } hv, ev;
    hv.v = *(const s8v*)(hp + ii*8);
    ev.v = *(const s8v*)(ep + ii*8);
    #pragma unroll
    for (int k = 0; k < 8; ++k){
      float xx = bfu2f(ev.uu[k]) + bfu2f(hv.uu[k]);
      p += wp[ii*8+k]*ftanh(xx);
    }
  }
  p += __shfl_xor(p,1); p += __shfl_xor(p,2); p += __shfl_xor(p,4);
  if (part == 0) scl[b] = p;
  __syncthreads();
  if (tid < 32){
    float v = scl[tid];
    float m = v;
    #pragma unroll
    for (int o = 1; o <= 16; o <<= 1) m = fmaxf(m, __shfl_xor(m, o));
    float e = __expf(v - m);
    float Z = e;
    #pragma unroll
    for (int o = 1; o <= 16; o <<= 1) Z += __shfl_xor(Z, o);
    wat[s*B_ + tid] = e/Z;
  }
}

// ---- decoder k3: glimpse weighted sum + GRU pointwise. 128 blocks ----
__global__ __launch_bounds__(256) void dec_k3(
  const float* __restrict__ gi_t,
  const bf16* __restrict__ encWgb, const float* __restrict__ gh,
  const float* __restrict__ wat,
  float* __restrict__ hfD, bf16* __restrict__ hd_w, bf16* __restrict__ hall_t)
{
  __shared__ float watst[64];
  __shared__ float part_[4][3][256];
  __shared__ bf16 hnewst[256];
  const int tid = threadIdx.x, bid = blockIdx.x;
  const int x = bid&7, g3 = bid>>3;
  const int db = 4*x + (g3&3), jq = g3>>2;
  const int jD = jq*256 + tid;
  if (tid < 64) watst[tid] = wat[tid*B_ + db];
  __syncthreads();
  const int lane = tid&63, wv = tid>>6;
  const int j0 = jq*256 + lane*4;
  f4 g0 = (f4){0,0,0,0}, g1 = (f4){0,0,0,0}, g2 = (f4){0,0,0,0};
  #pragma unroll 4
  for (int i = 0; i < 16; ++i){
    const int s2 = wv*16 + i;
    const float wt = watst[s2];
    const bf16* ro = encWgb + ((size_t)s2*B_ + db)*H3_;
    union{ ull u; unsigned short us[4]; } v0, v1, v2;
    v0.u = *(const ull*)(ro + j0);
    v1.u = *(const ull*)(ro + H_ + j0);
    v2.u = *(const ull*)(ro + 2*H_ + j0);
    #pragma unroll
    for (int k = 0; k < 4; ++k){
      g0[k] += wt*bfu2f(v0.us[k]);
      g1[k] += wt*bfu2f(v1.us[k]);
      g2[k] += wt*bfu2f(v2.us[k]);
    }
  }
  *(f4*)&part_[wv][0][lane*4] = g0;
  *(f4*)&part_[wv][1][lane*4] = g1;
  *(f4*)&part_[wv][2][lane*4] = g2;
  __syncthreads();
  float G0 = part_[0][0][tid]+part_[1][0][tid]+part_[2][0][tid]+part_[3][0][tid];
  float G1 = part_[0][1][tid]+part_[1][1][tid]+part_[2][1][tid]+part_[3][1][tid];
  float G2 = part_[0][2][tid]+part_[1][2][tid]+part_[2][2][tid]+part_[3][2][tid];
  const float* gp = gi_t + (size_t)db*H3_ + jD;
  float ir  = gp[0]    + G0;
  float iz  = gp[H_]   + G1;
  float inn = gp[2*H_] + G2;
  float hr_ = gh[(size_t)db*H3_ + jD];
  float hz_ = gh[(size_t)db*H3_ + H_ + jD];
  float hn_ = gh[(size_t)db*H3_ + 2*H_ + jD];
  float rg = fsigmoid(ir + hr_);
  float zg = fsigmoid(iz + hz_);
  float ng = ftanh(inn + rg*hn_);
  float hold = hfD[(size_t)db*H_ + jD];
  float hnew = (1.f - zg)*ng + zg*hold;
  hfD[(size_t)db*H_ + jD] = hnew;
  hnewst[tid] = f2b(hnew);
  __syncthreads();
  if (tid < 64){
    ull v = *(ull*)&hnewst[tid*4];
    *(ull*)(hd_w + (size_t)db*H_ + jq*256 + tid*4) = v;
    *(ull*)(hall_t + (size_t)db*H_ + jq*256 + tid*4) = v;
  }
}

extern "C" void kernel_launch(void* const* d_in, const int* in_sizes, int n_in,
                              void* d_out, int out_size, void* d_ws, size_t ws_size,
                              hipStream_t stream)
{
  (void)in_sizes; (void)n_in; (void)out_size; (void)ws_size;
  const int*   iseq  = (const int*)d_in[0];
  const int*   tseq  = (const int*)d_in[1];
  const float* emb   = (const float*)d_in[2];
  const float* wihf  = (const float*)d_in[3];
  const float* whhf_f= (const float*)d_in[4];
  const float* bihf  = (const float*)d_in[5];
  const float* bhhf  = (const float*)d_in[6];
  const float* wihb  = (const float*)d_in[7];
  const float* whhb_f= (const float*)d_in[8];
  const float* bihb  = (const float*)d_in[9];
  const float* bhhb  = (const float*)d_in[10];
  const float* einit = (const float*)d_in[11];
  const float* wihd  = (const float*)d_in[12];
  const float* whhd_f= (const float*)d_in[13];
  const float* bihd  = (const float*)d_in[14];
  const float* bhhd  = (const float*)d_in[15];
  const float* dinh  = (const float*)d_in[16];
  const float* dino  = (const float*)d_in[17];
  const float* w1    = (const float*)d_in[18];
  const float* w2    = (const float*)d_in[19];
  const float* outw  = (const float*)d_in[20];
  const float* outb  = (const float*)d_in[21];
  float* out = (float*)d_out;

  char* ws = (char*)d_ws;
  size_t off = 0;
  auto alloc = [&](size_t bytes)->char*{ char* p = ws + off; off += (bytes + 255) & ~(size_t)255; return p; };
  // ---- FRONT POOL: all dead before the output stage; logits_b (131.07 MB) aliases it ----
  bf16* logits_b = (bf16*)ws;                              // [2048][32000] bf16
  bf16* x_b      = (bf16*)alloc((size_t)2048*512*2);
  bf16* lo_b     = (bf16*)alloc((size_t)2048*512*2);
  bf16* wihf_b   = (bf16*)alloc((size_t)3072*512*2);       // adjacent to wihb_b (forms [6144][512])
  bf16* wihb_b   = (bf16*)alloc((size_t)3072*512*2);
  bf16* whhf_b   = (bf16*)alloc((size_t)3072*1024*2);
  bf16* whhb_b   = (bf16*)alloc((size_t)3072*1024*2);
  bf16* wihd_b   = (bf16*)alloc((size_t)3072*3072*2);
  bf16* whhd_b   = (bf16*)alloc((size_t)3072*1024*2);
  bf16* w1_b     = (bf16*)alloc((size_t)1024*3072*2);
  float* gi_fb   = (float*)alloc((size_t)2048*6144*4);
  float* gi_d    = (float*)alloc((size_t)2048*3072*4);
  bf16* enc_b    = (bf16*)alloc((size_t)2048*2048*2);      // front pool ends ≥131.07 MB here
  // ---- persistent-small + tail (NOT aliased) ----
  bf16* encW1_b  = (bf16*)alloc((size_t)2048*1024*2);
  bf16* encWg_b  = (bf16*)alloc((size_t)2048*3072*2);
  float* bias_fb = (float*)alloc((size_t)6144*4);
  bf16*  henc_b  = (bf16*)alloc((size_t)2*65536*2);
  float* hfE     = (float*)alloc((size_t)2*32768*4);
  bf16*  hdb     = (bf16*)alloc((size_t)2*32768*2);
  float* hfD     = (float*)alloc((size_t)32768*4);
  bf16*  hW1b    = (bf16*)alloc((size_t)32768*2);
  float* ghb     = (float*)alloc((size_t)32*3072*4);
  float* wat     = (float*)alloc((size_t)64*32*4);
  float* rowM    = (float*)alloc((size_t)2048*4);
  float* rowL    = (float*)alloc((size_t)2048*4);
  bf16* outw_b   = (bf16*)alloc((size_t)32000*1024*2);
  bf16*  hall_b  = (bf16*)alloc((size_t)2048*1024*2);

  prep_all_k<<<dim3(512,12), 256, 0, stream>>>(
      emb, iseq, tseq, dino,
      wihf, wihb, whhf_f, whhb_f, whhd_f, w1, wihd, outw,
      einit, bihf, bihb, dinh,
      x_b, lo_b, wihf_b, wihb_b, whhf_b, whhb_b, whhd_b, w1_b, wihd_b, outw_b,
      henc_b, hfE, bias_fb, hdb, hfD);

  gemm_bt<0><<<dim3(48,16), 256, 0, stream>>>(x_b, 512, wihf_b, 512, bias_fb, gi_fb, 6144, 512);
  gemm_dual<<<dim3(24,16), 256, 0, stream>>>(x_b, lo_b, wihd_b, bihd, gi_d);

  for (int s = 0; s < 64; ++s){
    const bf16* hrd = henc_b + (size_t)(s&1)*65536;
    bf16*       hwr = henc_b + (size_t)((s+1)&1)*65536;
    enc_step_k<<<64, 256, 0, stream>>>(gi_fb, whhf_b, whhb_b, bhhf, bhhb,
                                       hrd, hwr, hfE, enc_b, s);
  }

  gemm_bt<1><<<dim3(8,16),  256, 0, stream>>>(enc_b, 2048, w1_b,       3072, nullptr, encW1_b, 1024, 2048);
  gemm_bt<1><<<dim3(24,16), 256, 0, stream>>>(enc_b, 2048, wihd_b+512, 3072, nullptr, encWg_b, 3072, 2048);

  for (int t = 0; t < 64; ++t){
    const bf16* hdr = hdb + (size_t)(t&1)*32768;
    bf16*       hdw = hdb + (size_t)((t+1)&1)*32768;
    dec_k1<<<64, 256, 0, stream>>>(hdr, whhd_b, bhhd, w1_b, ghb, hW1b);
    dec_k2<<<64, 256, 0, stream>>>(encW1_b, hW1b, w2, wat);
    dec_k3<<<128, 256, 0, stream>>>(gi_d + (size_t)t*B_*H3_, encWg_b, ghb, wat,
                                    hfD, hdw, hall_b + (size_t)t*B_*H_);
  }

  out_gemm_k<<<4096, 256, 0, stream>>>(hall_b, outw_b, outb, logits_b);
  logit_stats_k<<<2048, 256, 0, stream>>>(logits_b, rowM, rowL);
  norm_k<<<2048, 256, 0, stream>>>(logits_b, rowM, rowL, out);
}